// Round 10
// baseline (626.264 us; speedup 1.0000x reference)
//
#include <hip/hip_runtime.h>

// ---------------------------------------------------------------------------
// GCN: 3x (GCNConv -> BatchNorm -> ReLU) -> global_add_pool -> MLP
// Layer 1 aggregates in 128-dim input space (A(XW) == (AX)W, half gather
// bytes). bf16 MFMA GEMM (BN of prev layer fused into A-staging for L2/L3).
// CSR gather is throughput-bound on random rows -> byte reduction, not ILP.
// ---------------------------------------------------------------------------

typedef __attribute__((ext_vector_type(8))) short bf16x8;
typedef __attribute__((ext_vector_type(4))) float f32x4;

__device__ inline float bf2f(unsigned short u) {
    union { unsigned int i; float f; } v; v.i = ((unsigned int)u) << 16; return v.f;
}
__device__ inline unsigned short f2bf(float f) {
    unsigned int x = __float_as_uint(f);
    unsigned int r = (x + 0x7FFFu + ((x >> 16) & 1u)) >> 16;
    return (unsigned short)r;
}
__device__ inline float4 ld4u(const unsigned short* p) {
    ushort4 u = *(const ushort4*)(p);
    return make_float4(bf2f(u.x), bf2f(u.y), bf2f(u.z), bf2f(u.w));
}
__device__ inline void st4u(unsigned short* p, float4 v) {
    ushort4 u; u.x = f2bf(v.x); u.y = f2bf(v.y); u.z = f2bf(v.z); u.w = f2bf(v.w);
    *(ushort4*)p = u;
}
__device__ inline float2 ld2u(const unsigned short* p) {
    ushort2 u = *(const ushort2*)(p);
    return make_float2(bf2f(u.x), bf2f(u.y));
}
__device__ inline void st2u(unsigned short* p, float2 v) {
    ushort2 u; u.x = f2bf(v.x); u.y = f2bf(v.y);
    *(ushort2*)p = u;
}

// ---- CSR build -------------------------------------------------------------
__global__ void count_deg_i(const int* __restrict__ dst, int* __restrict__ deg, int E) {
    int i = blockIdx.x * blockDim.x + threadIdx.x;
    int stride = gridDim.x * blockDim.x;
    for (; i < E; i += stride) atomicAdd(&deg[dst[i]], 1);
}

__global__ __launch_bounds__(256) void scan_partial(
    const int* __restrict__ deg, int* __restrict__ psum, int N)
{
    __shared__ int red[256];
    const int t = threadIdx.x;
    const int i0 = blockIdx.x * 512 + t * 2;
    int s = 0;
    if (i0 < N) s += deg[i0];
    if (i0 + 1 < N) s += deg[i0 + 1];
    red[t] = s;
    __syncthreads();
    for (int off = 128; off > 0; off >>= 1) {
        if (t < off) red[t] += red[t + off];
        __syncthreads();
    }
    if (t == 0) psum[blockIdx.x] = red[0];
}

__global__ __launch_bounds__(1024) void scan_offsets(
    const int* __restrict__ psum, int* __restrict__ poff, int NB,
    int* __restrict__ rowptr, int N)
{
    __shared__ int s[1024];
    const int t = threadIdx.x;
    int v = (t < NB) ? psum[t] : 0;
    s[t] = v;
    __syncthreads();
    for (int off = 1; off < 1024; off <<= 1) {
        int u = (t >= off) ? s[t - off] : 0;
        __syncthreads();
        s[t] += u;
        __syncthreads();
    }
    if (t < NB) poff[t] = s[t] - v;
    if (t == 1023) rowptr[N] = s[1023];
}

__global__ __launch_bounds__(256) void write_rowptr(
    const int* __restrict__ deg, const int* __restrict__ poff,
    int* __restrict__ rowptr, int N)
{
    __shared__ int s[256];
    const int t = threadIdx.x;
    const int i0 = blockIdx.x * 512 + t * 2;
    int e0 = (i0 < N) ? deg[i0] : 0;
    int e1 = (i0 + 1 < N) ? deg[i0 + 1] : 0;
    int sum = e0 + e1;
    s[t] = sum;
    __syncthreads();
    for (int off = 1; off < 256; off <<= 1) {
        int u = (t >= off) ? s[t - off] : 0;
        __syncthreads();
        s[t] += u;
        __syncthreads();
    }
    int excl = s[t] - sum + poff[blockIdx.x];
    if (i0 < N) rowptr[i0] = excl;
    if (i0 + 1 < N) rowptr[i0 + 1] = excl + e0;
}

__global__ void dinv_from_rowptr(const int* __restrict__ rowptr, float* __restrict__ dinv, int N) {
    int i = blockIdx.x * blockDim.x + threadIdx.x;
    if (i < N) dinv[i] = rsqrtf((float)(rowptr[i + 1] - rowptr[i]) + 1.0f);
}

__global__ void fill_csr(const int* __restrict__ src, const int* __restrict__ dst,
                         const int* __restrict__ rowptr, int* __restrict__ cnt,
                         int* __restrict__ col, int E)
{
    int i = blockIdx.x * blockDim.x + threadIdx.x;
    int stride = gridDim.x * blockDim.x;
    for (; i < E; i += stride) {
        int d = dst[i];
        int pos = atomicAdd(&cnt[d], 1);
        col[rowptr[d] + pos] = src[i];
    }
}

// ---- weight transpose (all 3 layers, one launch) ----------------------------
__global__ void make_wt_all(const float* __restrict__ W1, const float* __restrict__ W2,
                            const float* __restrict__ W3,
                            unsigned short* __restrict__ T1, unsigned short* __restrict__ T2,
                            unsigned short* __restrict__ T3)
{
    int i = blockIdx.x * blockDim.x + threadIdx.x;
    if (i < 128 * 256) {
        int k = i >> 8, n = i & 255;
        T1[n * 128 + k] = f2bf(W1[i]);
    } else if (i < 128 * 256 + 256 * 256) {
        int j = i - 128 * 256;
        int k = j >> 8, n = j & 255;
        T2[n * 256 + k] = f2bf(W2[j]);
    } else if (i < 128 * 256 + 2 * 256 * 256) {
        int j = i - 128 * 256 - 256 * 256;
        int k = j >> 8, n = j & 255;
        T3[n * 256 + k] = f2bf(W3[j]);
    }
}

// ---- x~ = x * dinv[row], fp32[N][128] -> bf16 -------------------------------
__global__ void conv_xt(const float* __restrict__ in, const float* __restrict__ dinv,
                        unsigned short* __restrict__ out, int N)
{
    size_t n4 = (size_t)N * 32;   // float4s (128 cols = 32 float4/row)
    size_t stride = (size_t)gridDim.x * blockDim.x;
    const float4* in4 = (const float4*)in;
    for (size_t i = blockIdx.x * (size_t)blockDim.x + threadIdx.x; i < n4; i += stride) {
        int row = (int)(i >> 5);
        float di = dinv[row];
        float4 v = in4[i];
        v.x *= di; v.y *= di; v.z *= di; v.w *= di;
        st4u(out + i * 4, v);
    }
}

// ---- 128-dim CSR gather: a~[n] = bf16(dinv[n]*(x~[n] + sum x~[src])) --------
__global__ __launch_bounds__(256) void gather_in(
    const unsigned short* __restrict__ xt, const int* __restrict__ rowptr,
    const int* __restrict__ col, const float* __restrict__ dinv,
    unsigned short* __restrict__ aout, int N)
{
    const int lane = threadIdx.x & 63;
    const int c2 = lane * 2;
    const int w = (blockIdx.x * blockDim.x + threadIdx.x) >> 6;
    const int nw = (gridDim.x * blockDim.x) >> 6;

    for (int n0 = w; n0 < N; n0 += nw * 4) {
        const int nA = n0, nB = n0 + nw, nC = n0 + 2 * nw, nD = n0 + 3 * nw;
        const bool hB = nB < N, hC = nC < N, hD = nD < N;

        int eA = rowptr[nA], eA1 = rowptr[nA + 1];
        int eB = 0, eB1 = 0, eC = 0, eC1 = 0, eD = 0, eD1 = 0;
        if (hB) { eB = rowptr[nB]; eB1 = rowptr[nB + 1]; }
        if (hC) { eC = rowptr[nC]; eC1 = rowptr[nC + 1]; }
        if (hD) { eD = rowptr[nD]; eD1 = rowptr[nD + 1]; }

        float2 aA = ld2u(xt + (size_t)nA * 128 + c2);
        float2 aB = make_float2(0.f, 0.f), aC = aB, aD = aB;
        if (hB) aB = ld2u(xt + (size_t)nB * 128 + c2);
        if (hC) aC = ld2u(xt + (size_t)nC * 128 + c2);
        if (hD) aD = ld2u(xt + (size_t)nD * 128 + c2);

        while ((eA < eA1) | (eB < eB1) | (eC < eC1) | (eD < eD1)) {
            int sA = -1, sB = -1, sC = -1, sD = -1;
            if (eA < eA1) sA = col[eA++];
            if (eB < eB1) sB = col[eB++];
            if (eC < eC1) sC = col[eC++];
            if (eD < eD1) sD = col[eD++];
            float2 vA, vB, vC, vD;
            if (sA >= 0) vA = ld2u(xt + (size_t)sA * 128 + c2);
            if (sB >= 0) vB = ld2u(xt + (size_t)sB * 128 + c2);
            if (sC >= 0) vC = ld2u(xt + (size_t)sC * 128 + c2);
            if (sD >= 0) vD = ld2u(xt + (size_t)sD * 128 + c2);
            if (sA >= 0) { aA.x += vA.x; aA.y += vA.y; }
            if (sB >= 0) { aB.x += vB.x; aB.y += vB.y; }
            if (sC >= 0) { aC.x += vC.x; aC.y += vC.y; }
            if (sD >= 0) { aD.x += vD.x; aD.y += vD.y; }
        }

        { float di = dinv[nA]; st2u(aout + (size_t)nA * 128 + c2, make_float2(di * aA.x, di * aA.y)); }
        if (hB) { float di = dinv[nB]; st2u(aout + (size_t)nB * 128 + c2, make_float2(di * aB.x, di * aB.y)); }
        if (hC) { float di = dinv[nC]; st2u(aout + (size_t)nC * 128 + c2, make_float2(di * aC.x, di * aC.y)); }
        if (hD) { float di = dinv[nD]; st2u(aout + (size_t)nD * 128 + c2, make_float2(di * aD.x, di * aD.y)); }
    }
}

// ---- fused BN helper: 8 bf16 -> relu(v*sc+sh) -> 8 bf16 --------------------
__device__ inline unsigned int bn2(unsigned int w, float sL, float hL, float sH, float hH) {
    float lo = bf2f((unsigned short)(w & 0xFFFFu));
    float hi = bf2f((unsigned short)(w >> 16));
    lo = fmaxf(fmaf(lo, sL, hL), 0.f);
    hi = fmaxf(fmaf(hi, sH, hH), 0.f);
    return (unsigned int)f2bf(lo) | ((unsigned int)f2bf(hi) << 16);
}
__device__ inline uint4 bn8(uint4 v, const float* __restrict__ ss, int c) {
    float4 sA = *(const float4*)(ss + c);
    float4 sB = *(const float4*)(ss + c + 4);
    float4 hA = *(const float4*)(ss + 256 + c);
    float4 hB = *(const float4*)(ss + 256 + c + 4);
    uint4 r;
    r.x = bn2(v.x, sA.x, hA.x, sA.y, hA.y);
    r.y = bn2(v.y, sA.z, hA.z, sA.w, hA.w);
    r.z = bn2(v.z, sB.x, hB.x, sB.y, hB.y);
    r.w = bn2(v.w, sB.z, hB.z, sB.w, hB.w);
    return r;
}

// ---- bf16 MFMA GEMM, 128x128 tile, BK=32, XCD-paired 1D grid ---------------
// FUSE_BN: apply relu(a*sc+sh) to A during staging.
// EPI=0: C = acc * dinv[row]   EPI=1: C = acc + bias[col]
template<int FUSE_BN, int EPI>
__global__ __launch_bounds__(256) void gemm_mfma(
    const unsigned short* __restrict__ A,
    const unsigned short* __restrict__ WT,
    const float* __restrict__ dinv,
    const float* __restrict__ ss,
    const float* __restrict__ bias,
    unsigned short* __restrict__ C,
    int K, int nbx)
{
    // XCD-paired swizzle: blocks id and id+8 share the same A-panel and land
    // on the same XCD (dispatch round-robins XCDs by id&7) -> A reuse in L2.
    const int id = blockIdx.x;
    const int main2 = (nbx & ~7) * 2;
    int bx, by;
    if (id < main2) {
        bx = (id >> 4) * 8 + (id & 7);
        by = (id >> 3) & 1;
    } else {
        int r = id - main2;
        bx = (nbx & ~7) + (r >> 1);
        by = r & 1;
    }

    __shared__ unsigned short As[128 * 32];
    __shared__ unsigned short Bs[128 * 32];

    const int tid = threadIdx.x;
    const int bm = bx * 128;
    const int bn = by * 128;
    const int lane = tid & 63;
    const int wid = tid >> 6;
    const int wr = wid >> 1;
    const int wc = wid & 1;
    const int r0 = tid >> 2;
    const int cc0 = tid & 3;

    f32x4 acc[4][4];
    #pragma unroll
    for (int m = 0; m < 4; ++m)
        #pragma unroll
        for (int n = 0; n < 4; ++n)
            acc[m][n] = (f32x4){0.f, 0.f, 0.f, 0.f};

    uint4* AsV = (uint4*)As;
    uint4* BsV = (uint4*)Bs;

    for (int k0 = 0; k0 < K; k0 += 32) {
        if (k0) __syncthreads();
        {
            const int gcc = (cc0 ^ (r0 & 3)) * 8;
            uint4 va0 = *(const uint4*)(A  + (size_t)(bm + r0)      * K + k0 + gcc);
            uint4 vb0 = *(const uint4*)(WT + (size_t)(bn + r0)      * K + k0 + gcc);
            uint4 va1 = *(const uint4*)(A  + (size_t)(bm + r0 + 64) * K + k0 + gcc);
            uint4 vb1 = *(const uint4*)(WT + (size_t)(bn + r0 + 64) * K + k0 + gcc);
            if (FUSE_BN) {
                va0 = bn8(va0, ss, k0 + gcc);
                va1 = bn8(va1, ss, k0 + gcc);
            }
            AsV[r0 * 4 + cc0]        = va0;
            AsV[(r0 + 64) * 4 + cc0] = va1;
            BsV[r0 * 4 + cc0]        = vb0;
            BsV[(r0 + 64) * 4 + cc0] = vb1;
        }
        __syncthreads();

        bf16x8 af[4], bfv[4];
        #pragma unroll
        for (int n = 0; n < 4; ++n) {
            int R = wc * 64 + n * 16 + (lane & 15);
            int pc = (lane >> 4) ^ (R & 3);
            af[n] = *(const bf16x8*)&Bs[R * 32 + pc * 8];
        }
        #pragma unroll
        for (int m = 0; m < 4; ++m) {
            int R = wr * 64 + m * 16 + (lane & 15);
            int pc = (lane >> 4) ^ (R & 3);
            bfv[m] = *(const bf16x8*)&As[R * 32 + pc * 8];
        }
        #pragma unroll
        for (int m = 0; m < 4; ++m)
            #pragma unroll
            for (int n = 0; n < 4; ++n)
                acc[m][n] = __builtin_amdgcn_mfma_f32_16x16x32_bf16(
                    af[n], bfv[m], acc[m][n], 0, 0, 0);
    }

    #pragma unroll
    for (int m = 0; m < 4; ++m) {
        int row = bm + wr * 64 + m * 16 + (lane & 15);
        float di = (EPI == 0) ? dinv[row] : 0.f;
        #pragma unroll
        for (int n = 0; n < 4; ++n) {
            int cb = bn + wc * 64 + n * 16 + ((lane >> 4) << 2);
            ushort4 u;
            if (EPI == 0) {
                u.x = f2bf(acc[m][n][0] * di);
                u.y = f2bf(acc[m][n][1] * di);
                u.z = f2bf(acc[m][n][2] * di);
                u.w = f2bf(acc[m][n][3] * di);
            } else {
                float4 bv = *(const float4*)(bias + cb);
                u.x = f2bf(acc[m][n][0] + bv.x);
                u.y = f2bf(acc[m][n][1] + bv.y);
                u.z = f2bf(acc[m][n][2] + bv.z);
                u.w = f2bf(acc[m][n][3] + bv.w);
            }
            *(ushort4*)(C + (size_t)row * 256 + cb) = u;
        }
    }
}

// ---- column stats over t (bf16 [N][256]) -----------------------------------
__global__ __launch_bounds__(256) void t_stats(
    const unsigned short* __restrict__ t, float* __restrict__ stats, int N)
{
    const int f = threadIdx.x;
    float sum = 0.f, sq = 0.f;
    for (int r = blockIdx.x; r < N; r += gridDim.x) {
        float v = bf2f(t[(size_t)r * 256 + f]);
        sum += v; sq += v * v;
    }
    atomicAdd(&stats[f], sum);
    atomicAdd(&stats[256 + f], sq);
}

// ---- ILP-4 CSR gather + pre-BN activation + column stats (H=256) -----------
__global__ __launch_bounds__(256) void gather_bn(
    const unsigned short* __restrict__ xs, const int* __restrict__ rowptr,
    const int* __restrict__ col, const float* __restrict__ dinv,
    const float* __restrict__ b, unsigned short* __restrict__ t_out,
    float* __restrict__ stats, int N)
{
    __shared__ float lred[4][512];
    const int lane = threadIdx.x & 63;
    const int wid = threadIdx.x >> 6;
    const int c4 = lane * 4;
    const float4 bv = *(const float4*)(b + c4);

    float s0 = 0, s1 = 0, s2 = 0, s3 = 0;
    float q0 = 0, q1 = 0, q2 = 0, q3 = 0;

    const int w = (blockIdx.x * blockDim.x + threadIdx.x) >> 6;
    const int nw = (gridDim.x * blockDim.x) >> 6;

    for (int n0 = w; n0 < N; n0 += nw * 4) {
        const int nA = n0, nB = n0 + nw, nC = n0 + 2 * nw, nD = n0 + 3 * nw;
        const bool hB = nB < N, hC = nC < N, hD = nD < N;

        int eA = rowptr[nA], eA1 = rowptr[nA + 1];
        int eB = 0, eB1 = 0, eC = 0, eC1 = 0, eD = 0, eD1 = 0;
        if (hB) { eB = rowptr[nB]; eB1 = rowptr[nB + 1]; }
        if (hC) { eC = rowptr[nC]; eC1 = rowptr[nC + 1]; }
        if (hD) { eD = rowptr[nD]; eD1 = rowptr[nD + 1]; }

        float4 aA = ld4u(xs + (size_t)nA * 256 + c4);
        float4 aB = make_float4(0.f, 0.f, 0.f, 0.f), aC = aB, aD = aB;
        if (hB) aB = ld4u(xs + (size_t)nB * 256 + c4);
        if (hC) aC = ld4u(xs + (size_t)nC * 256 + c4);
        if (hD) aD = ld4u(xs + (size_t)nD * 256 + c4);

        while ((eA < eA1) | (eB < eB1) | (eC < eC1) | (eD < eD1)) {
            int sA = -1, sB = -1, sC = -1, sD = -1;
            if (eA < eA1) sA = col[eA++];
            if (eB < eB1) sB = col[eB++];
            if (eC < eC1) sC = col[eC++];
            if (eD < eD1) sD = col[eD++];
            float4 vA, vB, vC, vD;
            if (sA >= 0) vA = ld4u(xs + (size_t)sA * 256 + c4);
            if (sB >= 0) vB = ld4u(xs + (size_t)sB * 256 + c4);
            if (sC >= 0) vC = ld4u(xs + (size_t)sC * 256 + c4);
            if (sD >= 0) vD = ld4u(xs + (size_t)sD * 256 + c4);
            if (sA >= 0) { aA.x += vA.x; aA.y += vA.y; aA.z += vA.z; aA.w += vA.w; }
            if (sB >= 0) { aB.x += vB.x; aB.y += vB.y; aB.z += vB.z; aB.w += vB.w; }
            if (sC >= 0) { aC.x += vC.x; aC.y += vC.y; aC.z += vC.z; aC.w += vC.w; }
            if (sD >= 0) { aD.x += vD.x; aD.y += vD.y; aD.z += vD.z; aD.w += vD.w; }
        }

        {
            float di = dinv[nA];
            float4 t;
            t.x = fmaf(di, aA.x, bv.x); t.y = fmaf(di, aA.y, bv.y);
            t.z = fmaf(di, aA.z, bv.z); t.w = fmaf(di, aA.w, bv.w);
            st4u(t_out + (size_t)nA * 256 + c4, t);
            s0 += t.x; s1 += t.y; s2 += t.z; s3 += t.w;
            q0 += t.x * t.x; q1 += t.y * t.y; q2 += t.z * t.z; q3 += t.w * t.w;
        }
        if (hB) {
            float di = dinv[nB];
            float4 t;
            t.x = fmaf(di, aB.x, bv.x); t.y = fmaf(di, aB.y, bv.y);
            t.z = fmaf(di, aB.z, bv.z); t.w = fmaf(di, aB.w, bv.w);
            st4u(t_out + (size_t)nB * 256 + c4, t);
            s0 += t.x; s1 += t.y; s2 += t.z; s3 += t.w;
            q0 += t.x * t.x; q1 += t.y * t.y; q2 += t.z * t.z; q3 += t.w * t.w;
        }
        if (hC) {
            float di = dinv[nC];
            float4 t;
            t.x = fmaf(di, aC.x, bv.x); t.y = fmaf(di, aC.y, bv.y);
            t.z = fmaf(di, aC.z, bv.z); t.w = fmaf(di, aC.w, bv.w);
            st4u(t_out + (size_t)nC * 256 + c4, t);
            s0 += t.x; s1 += t.y; s2 += t.z; s3 += t.w;
            q0 += t.x * t.x; q1 += t.y * t.y; q2 += t.z * t.z; q3 += t.w * t.w;
        }
        if (hD) {
            float di = dinv[nD];
            float4 t;
            t.x = fmaf(di, aD.x, bv.x); t.y = fmaf(di, aD.y, bv.y);
            t.z = fmaf(di, aD.z, bv.z); t.w = fmaf(di, aD.w, bv.w);
            st4u(t_out + (size_t)nD * 256 + c4, t);
            s0 += t.x; s1 += t.y; s2 += t.z; s3 += t.w;
            q0 += t.x * t.x; q1 += t.y * t.y; q2 += t.z * t.z; q3 += t.w * t.w;
        }
    }

    lred[wid][c4 + 0] = s0; lred[wid][c4 + 1] = s1;
    lred[wid][c4 + 2] = s2; lred[wid][c4 + 3] = s3;
    lred[wid][256 + c4 + 0] = q0; lred[wid][256 + c4 + 1] = q1;
    lred[wid][256 + c4 + 2] = q2; lred[wid][256 + c4 + 3] = q3;
    __syncthreads();
    for (int i = threadIdx.x; i < 512; i += 256) {
        float v = lred[0][i] + lred[1][i] + lred[2][i] + lred[3][i];
        atomicAdd(&stats[i], v);
    }
}

// ---- bn_finalize: ss from stats, then zero stats for the next layer --------
__global__ void bn_finalize(float* __restrict__ stats,
                            const float* __restrict__ g, const float* __restrict__ be,
                            float* __restrict__ ss, int N)
{
    int f = threadIdx.x;
    float sm = stats[f];
    float sqv = stats[256 + f];
    float m = sm / (float)N;
    float v = sqv / (float)N - m * m;
    float sc = g[f] * rsqrtf(v + 1e-5f);
    ss[f] = sc;
    ss[256 + f] = be[f] - m * sc;
    stats[f] = 0.f;
    stats[256 + f] = 0.f;
}

// ---- pool (8 graphs/block) + MLP fused -------------------------------------
__global__ __launch_bounds__(256) void pool_mlp(
    const unsigned short* __restrict__ t, const int* __restrict__ batch,
    const float* __restrict__ ss,
    const float* __restrict__ LW1, const float* __restrict__ Lb1,
    const float* __restrict__ LW2, const float* __restrict__ Lb2,
    float* __restrict__ out, int N, int G)
{
    __shared__ int bnd[9];
    __shared__ float lred[4][256];
    __shared__ float sp[8][256];
    __shared__ float wpart[4][8];

    const int tid = threadIdx.x;
    const int g0 = blockIdx.x * 8;
    if (tid < 9) {
        int target = g0 + tid;
        int lo = 0, hi = N;
        while (lo < hi) { int m = (lo + hi) >> 1; if (batch[m] < target) lo = m + 1; else hi = m; }
        bnd[tid] = lo;
    }
    __syncthreads();

    const int lane = tid & 63;
    const int wid = tid >> 6;
    const int c4 = lane * 4;
    const float4 sc = *(const float4*)(ss + c4);
    const float4 sh = *(const float4*)(ss + 256 + c4);

    for (int j = 0; j < 8; ++j) {
        float4 acc = make_float4(0.f, 0.f, 0.f, 0.f);
        for (int r = bnd[j] + wid; r < bnd[j + 1]; r += 4) {
            float4 a = ld4u(t + (size_t)r * 256 + c4);
            acc.x += fmaxf(fmaf(a.x, sc.x, sh.x), 0.f);
            acc.y += fmaxf(fmaf(a.y, sc.y, sh.y), 0.f);
            acc.z += fmaxf(fmaf(a.z, sc.z, sh.z), 0.f);
            acc.w += fmaxf(fmaf(a.w, sc.w, sh.w), 0.f);
        }
        lred[wid][c4 + 0] = acc.x; lred[wid][c4 + 1] = acc.y;
        lred[wid][c4 + 2] = acc.z; lred[wid][c4 + 3] = acc.w;
        __syncthreads();
        sp[j][tid] = lred[0][tid] + lred[1][tid] + lred[2][tid] + lred[3][tid];
        __syncthreads();
    }

    // hidden = relu(sp @ LW1 + Lb1) for 8 graphs, sharing LW1 loads
    float acc8[8];
    float b1v = Lb1[tid];
    #pragma unroll
    for (int j = 0; j < 8; ++j) acc8[j] = b1v;
    for (int k = 0; k < 256; ++k) {
        float w = LW1[k * 256 + tid];
        #pragma unroll
        for (int j = 0; j < 8; ++j) acc8[j] = fmaf(sp[j][k], w, acc8[j]);
    }
    float w2 = LW2[tid];
    #pragma unroll
    for (int j = 0; j < 8; ++j) {
        float v = fmaxf(acc8[j], 0.f) * w2;
        #pragma unroll
        for (int off = 32; off > 0; off >>= 1) v += __shfl_down(v, off);
        if (lane == 0) wpart[wid][j] = v;
    }
    __syncthreads();
    if (tid < 8 && g0 + tid < G)
        out[g0 + tid] = wpart[0][tid] + wpart[1][tid] + wpart[2][tid] + wpart[3][tid] + Lb2[0];
}

// ---------------------------------------------------------------------------
extern "C" void kernel_launch(void* const* d_in, const int* in_sizes, int n_in,
                              void* d_out, int out_size, void* d_ws, size_t ws_size,
                              hipStream_t stream)
{
    const float* x    = (const float*)d_in[0];
    const int*   ei   = (const int*)d_in[1];
    const int*   batch= (const int*)d_in[2];
    const float* W1 = (const float*)d_in[3];  const float* b1 = (const float*)d_in[4];
    const float* W2 = (const float*)d_in[5];  const float* b2 = (const float*)d_in[6];
    const float* W3 = (const float*)d_in[7];  const float* b3 = (const float*)d_in[8];
    const float* g1 = (const float*)d_in[9];  const float* be1= (const float*)d_in[10];
    const float* g2 = (const float*)d_in[11]; const float* be2= (const float*)d_in[12];
    const float* g3 = (const float*)d_in[13]; const float* be3= (const float*)d_in[14];
    const float* LW1= (const float*)d_in[15]; const float* Lb1= (const float*)d_in[16];
    const float* LW2= (const float*)d_in[17]; const float* Lb2= (const float*)d_in[18];

    const int N = in_sizes[2];            // 100000
    const int E = in_sizes[1] / 2;        // 300000
    const int H = in_sizes[4];            // 256
    const int G = out_size;               // 2048
    const int Mp = (N + 127) & ~127;
    const int NB = (N + 511) / 512;
    const int nbx = Mp / 128;
    const int* src = ei;
    const int* dst = ei + E;
    const size_t NHp = (size_t)Mp * H;

    // ---- workspace layout ----
    char* p = (char*)d_ws;
    unsigned short* TB = (unsigned short*)p;  p += NHp * 2;   // t / x~ staging [Mp,256] bf16
    unsigned short* XS = (unsigned short*)p;  p += NHp * 2;   // xs / a~       [Mp,256] bf16
    float* dinv = (float*)p;           p += (((size_t)Mp * 4) + 255) & ~(size_t)255;
    int* degi  = (int*)p;              p += (((size_t)N * 4) + 255) & ~(size_t)255;
    float* stats = (float*)p;          p += 2048;
    float* ss    = (float*)p;          p += 2048;
    int* psum   = (int*)p;             p += 4096;
    int* poff   = (int*)p;             p += 4096;
    int* rowptr = (int*)p;             p += (((size_t)(N + 1) * 4) + 255) & ~(size_t)255;
    int* col    = (int*)p;             p += (((size_t)E * 4) + 255) & ~(size_t)255;
    unsigned short* WT1 = (unsigned short*)p;  p += (size_t)128 * 256 * 2;
    unsigned short* WT2 = (unsigned short*)p;  p += (size_t)256 * 256 * 2;
    unsigned short* WT3 = (unsigned short*)p;  p += (size_t)256 * 256 * 2;

    // CSR build + dinv
    hipMemsetAsync(degi, 0, (size_t)N * sizeof(int), stream);
    hipMemsetAsync(stats, 0, 512 * sizeof(float), stream);
    count_deg_i<<<1024, 256, 0, stream>>>(dst, degi, E);
    scan_partial<<<NB, 256, 0, stream>>>(degi, psum, N);
    scan_offsets<<<1, 1024, 0, stream>>>(psum, poff, NB, rowptr, N);
    write_rowptr<<<NB, 256, 0, stream>>>(degi, poff, rowptr, N);
    dinv_from_rowptr<<<(N + 255) / 256, 256, 0, stream>>>(rowptr, dinv, N);
    hipMemsetAsync(degi, 0, (size_t)N * sizeof(int), stream);
    fill_csr<<<1024, 256, 0, stream>>>(src, dst, rowptr, degi, col, E);

    make_wt_all<<<(128 * 256 + 2 * 256 * 256 + 255) / 256, 256, 0, stream>>>(
        W1, W2, W3, WT1, WT2, WT3);

    // ---- layer 1 (aggregate in 128-dim input space) ----
    conv_xt<<<2048, 256, 0, stream>>>(x, dinv, TB, N);                 // x~ -> TB[.][128]
    gather_in<<<2048, 256, 0, stream>>>(TB, rowptr, col, dinv, XS, N); // a~ -> XS[.][128]
    gemm_mfma<0, 1><<<nbx * 2, 256, 0, stream>>>(XS, WT1, dinv, nullptr, b1, TB, 128, nbx);
    t_stats<<<1024, 256, 0, stream>>>(TB, stats, N);
    bn_finalize<<<1, 256, 0, stream>>>(stats, g1, be1, ss, N);

    // ---- layers 2,3 ----
    gemm_mfma<1, 0><<<nbx * 2, 256, 0, stream>>>(TB, WT2, dinv, ss, nullptr, XS, 256, nbx);
    gather_bn<<<2048, 256, 0, stream>>>(XS, rowptr, col, dinv, b2, TB, stats, N);
    bn_finalize<<<1, 256, 0, stream>>>(stats, g2, be2, ss, N);

    gemm_mfma<1, 0><<<nbx * 2, 256, 0, stream>>>(TB, WT3, dinv, ss, nullptr, XS, 256, nbx);
    gather_bn<<<2048, 256, 0, stream>>>(XS, rowptr, col, dinv, b3, TB, stats, N);
    bn_finalize<<<1, 256, 0, stream>>>(stats, g3, be3, ss, N);

    // ---- pool + MLP ----
    pool_mlp<<<(G + 7) / 8, 256, 0, stream>>>(TB, batch, ss, LW1, Lb1, LW2, Lb2,
                                              (float*)d_out, N, G);
}